// Round 15
// baseline (111.849 us; speedup 1.0000x reference)
//
#include <hip/hip_runtime.h>
#include <math.h>

#define NB 8
#define NA 1024
#define NN 64
#define NF 128
#define NS 64
#define APB 4      // atoms (b,a) processed per block
#define LN2 0.69314718055994530942f
#define HSTR 136   // bf16 LDS row stride in elems: 272B rows, balanced b128 reads

typedef __attribute__((ext_vector_type(8))) short bf16x8;
typedef __attribute__((ext_vector_type(4))) float f32x4;
typedef __attribute__((ext_vector_type(4))) unsigned u32x4;

__device__ __forceinline__ float ssp(float x) {
    return fmaxf(x, 0.0f) + __logf(1.0f + __expf(-fabsf(x))) - LN2;
}
__device__ __forceinline__ short f2bf(float f) {      // RNE f32 -> bf16 (cold paths)
    unsigned u = __float_as_uint(f);
    u += 0x7fffu + ((u >> 16) & 1u);
    return (short)(u >> 16);
}
__device__ __forceinline__ unsigned pkbf(float a, float b) {   // packed RNE pair, 1 inst
    unsigned r;
    asm("v_cvt_pk_bf16_f32 %0, %1, %2" : "=v"(r) : "v"(a), "v"(b));
    return r;
}
__device__ __forceinline__ float bf2f(short s) {
    return __uint_as_float(((unsigned)(unsigned short)s) << 16);
}

// ---------------- prep: swizzle weights into MFMA B-fragment order (bf16) ----------------
__device__ __forceinline__ void swz_frag(const float* __restrict__ W, short* __restrict__ Wf, int t) {
    int k = t >> 7, n = t & 127;
    int kt = k >> 5, lg = (k >> 3) & 3, j = k & 7, ntg = n >> 4, col = n & 15;
    Wf[((kt * 8 + ntg) * 64 + (lg * 16 + col)) * 8 + j] = f2bf(W[t]);
}

__global__ __launch_bounds__(256) void k_prep(const float* __restrict__ W1,
                                              const float* __restrict__ W2,
                                              const float* __restrict__ Winf,
                                              const float* __restrict__ Wf2,
                                              const float* __restrict__ Wd,
                                              short* __restrict__ W1f, short* __restrict__ W2f,
                                              short* __restrict__ Winff, short* __restrict__ Wf2f,
                                              short* __restrict__ Wdf) {
    int t = blockIdx.x * 256 + threadIdx.x;   // 16384 threads == NF*NF
    if (t < NS * NF) swz_frag(W1, W1f, t);
    swz_frag(W2, W2f, t);
    swz_frag(Winf, Winff, t);
    swz_frag(Wf2, Wf2f, t);
    swz_frag(Wd, Wdf, t);
}

// ---- staging helper: 32 f32 rows (128 wide) -> bf16 LDS, XOR-swizzled, 256B rows ----
__device__ __forceinline__ void stage32(const float* __restrict__ src, char* __restrict__ dst, int t) {
    int row = t >> 3, seg = t & 7;
    const float4* sp = (const float4*)(src + (size_t)row * NF + seg * 16);
    float4 a = sp[0], b = sp[1], c = sp[2], d = sp[3];
    u32x4 lo = (u32x4){pkbf(a.x, a.y), pkbf(a.z, a.w), pkbf(b.x, b.y), pkbf(b.z, b.w)};
    u32x4 hi = (u32x4){pkbf(c.x, c.y), pkbf(c.z, c.w), pkbf(d.x, d.y), pkbf(d.z, d.w)};
    int base = row * 256 + seg * 32;
    int sw = (row & 7) << 4;
    *(u32x4*)(dst + ((base) ^ sw))      = lo;
    *(u32x4*)(dst + ((base + 16) ^ sw)) = hi;
}

// ---------------- kernel 1: y = x @ W_in2f (no bias), MFMA, M=32/block ----------------
__global__ __launch_bounds__(256) void k_in2f_m(const float* __restrict__ x,
                                                const short* __restrict__ Wf,
                                                float* __restrict__ y) {
    __shared__ __align__(16) char xL[32 * 256];   // 8 KB
    int t = threadIdx.x, lane = t & 63, wid = t >> 6;
    int row0 = blockIdx.x * 32;

    stage32(x + (size_t)row0 * NF, xL, t);
    __syncthreads();

    int rowA = lane & 15, kgrp = lane >> 4, goff = wid * 32;
    f32x4 acc[2][2];
#pragma unroll
    for (int mt = 0; mt < 2; mt++) {
        acc[mt][0] = (f32x4){0.f, 0.f, 0.f, 0.f};
        acc[mt][1] = (f32x4){0.f, 0.f, 0.f, 0.f};
    }
#pragma unroll
    for (int kt = 0; kt < 4; kt++) {
        bf16x8 bf0 = *(const bf16x8*)&Wf[((kt * 8 + wid * 2 + 0) * 64 + lane) * 8];
        bf16x8 bf1 = *(const bf16x8*)&Wf[((kt * 8 + wid * 2 + 1) * 64 + lane) * 8];
#pragma unroll
        for (int mt = 0; mt < 2; mt++) {
            int row = mt * 16 + rowA;
            int byte = (row * 256 + kt * 64 + kgrp * 16) ^ ((row & 7) << 4);
            bf16x8 af = *(const bf16x8*)(xL + byte);
            acc[mt][0] = __builtin_amdgcn_mfma_f32_16x16x32_bf16(af, bf0, acc[mt][0], 0, 0, 0);
            acc[mt][1] = __builtin_amdgcn_mfma_f32_16x16x32_bf16(af, bf1, acc[mt][1], 0, 0, 0);
        }
    }
#pragma unroll
    for (int mt = 0; mt < 2; mt++)
#pragma unroll
        for (int nt = 0; nt < 2; nt++)
#pragma unroll
            for (int r = 0; r < 4; r++)
                y[(size_t)(row0 + mt * 16 + kgrp * 4 + r) * NF + goff + nt * 16 + (lane & 15)] = acc[mt][nt][r];
}

// ---------------- kernel 3: buf = ssp(buf@Wf2+bf2) @ Wd + bd, MFMA, in place, M=32/block ----------------
__global__ __launch_bounds__(256) void k_out_m(float* buf,
                                               const short* __restrict__ Wf2f, const float* __restrict__ bf2,
                                               const short* __restrict__ Wdf, const float* __restrict__ bd) {
    __shared__ __align__(16) char xL[32 * 256];   // 8 KB (agg bf16)
    __shared__ short vL[32 * HSTR];               // 8.5 KB (v bf16)
    int t = threadIdx.x, lane = t & 63, wid = t >> 6;
    int row0 = blockIdx.x * 32;

    stage32(buf + (size_t)row0 * NF, xL, t);
    __syncthreads();

    int rowA = lane & 15, kgrp = lane >> 4, goff = wid * 32;
    int gc0 = goff + (lane & 15), gc1 = gc0 + 16;
    float bb0 = bf2[gc0], bb1 = bf2[gc1];

    // GEMM1: v = ssp(agg @ Wf2 + bf2)
    f32x4 acc[2][2];
#pragma unroll
    for (int mt = 0; mt < 2; mt++) {
        acc[mt][0] = (f32x4){bb0, bb0, bb0, bb0};
        acc[mt][1] = (f32x4){bb1, bb1, bb1, bb1};
    }
#pragma unroll
    for (int kt = 0; kt < 4; kt++) {
        bf16x8 bf0 = *(const bf16x8*)&Wf2f[((kt * 8 + wid * 2 + 0) * 64 + lane) * 8];
        bf16x8 bf1 = *(const bf16x8*)&Wf2f[((kt * 8 + wid * 2 + 1) * 64 + lane) * 8];
#pragma unroll
        for (int mt = 0; mt < 2; mt++) {
            int row = mt * 16 + rowA;
            int byte = (row * 256 + kt * 64 + kgrp * 16) ^ ((row & 7) << 4);
            bf16x8 af = *(const bf16x8*)(xL + byte);
            acc[mt][0] = __builtin_amdgcn_mfma_f32_16x16x32_bf16(af, bf0, acc[mt][0], 0, 0, 0);
            acc[mt][1] = __builtin_amdgcn_mfma_f32_16x16x32_bf16(af, bf1, acc[mt][1], 0, 0, 0);
        }
    }
    // ssp -> vL (bf16, HSTR rows)
#pragma unroll
    for (int mt = 0; mt < 2; mt++)
#pragma unroll
        for (int nt = 0; nt < 2; nt++) {
            int col = goff + nt * 16 + (lane & 15);
            int r0 = mt * 16 + kgrp * 4;
            unsigned p01 = pkbf(ssp(acc[mt][nt][0]), ssp(acc[mt][nt][1]));
            unsigned p23 = pkbf(ssp(acc[mt][nt][2]), ssp(acc[mt][nt][3]));
            vL[(r0 + 0) * HSTR + col] = (short)(p01 & 0xffffu);
            vL[(r0 + 1) * HSTR + col] = (short)(p01 >> 16);
            vL[(r0 + 2) * HSTR + col] = (short)(p23 & 0xffffu);
            vL[(r0 + 3) * HSTR + col] = (short)(p23 >> 16);
        }
    __syncthreads();

    // GEMM2: out = v @ Wd + bd
    float bd0 = bd[gc0], bd1 = bd[gc1];
    f32x4 acc2[2][2];
#pragma unroll
    for (int mt = 0; mt < 2; mt++) {
        acc2[mt][0] = (f32x4){bd0, bd0, bd0, bd0};
        acc2[mt][1] = (f32x4){bd1, bd1, bd1, bd1};
    }
#pragma unroll
    for (int kt = 0; kt < 4; kt++) {
        bf16x8 bf0 = *(const bf16x8*)&Wdf[((kt * 8 + wid * 2 + 0) * 64 + lane) * 8];
        bf16x8 bf1 = *(const bf16x8*)&Wdf[((kt * 8 + wid * 2 + 1) * 64 + lane) * 8];
#pragma unroll
        for (int mt = 0; mt < 2; mt++) {
            bf16x8 af = *(const bf16x8*)&vL[(mt * 16 + rowA) * HSTR + kt * 32 + kgrp * 8];
            acc2[mt][0] = __builtin_amdgcn_mfma_f32_16x16x32_bf16(af, bf0, acc2[mt][0], 0, 0, 0);
            acc2[mt][1] = __builtin_amdgcn_mfma_f32_16x16x32_bf16(af, bf1, acc2[mt][1], 0, 0, 0);
        }
    }
#pragma unroll
    for (int mt = 0; mt < 2; mt++)
#pragma unroll
        for (int nt = 0; nt < 2; nt++)
#pragma unroll
            for (int r = 0; r < 4; r++)
                buf[(size_t)(row0 + mt * 16 + kgrp * 4 + r) * NF + goff + nt * 16 + (lane & 15)] = acc2[mt][nt][r];
}

// ---------------- kernel 2: MFMA filter net + cfconv (4 atoms per block) ----------------
// grid = rows/APB; per atom: identical math to round-14 (overlaid 17.4K LDS union)
__global__ __launch_bounds__(256) void k_conv(
        const float* __restrict__ fij, const float* __restrict__ rij,
        const int* __restrict__ nbr, const int* __restrict__ nmask,
        const float* __restrict__ y,
        const short* __restrict__ W1f, const float* __restrict__ b1,
        const short* __restrict__ W2f, const float* __restrict__ b2,
        float* __restrict__ agg) {
    __shared__ __align__(16) char smem[NN * HSTR * 2];   // 17408 B union
    __shared__ int cOff[NN];            // compacted neighbor row offset (premul NF)
    __shared__ float2 red2[4][NF / 2];  // 2 KB

    short* hL  = (short*)smem;
    short* wfB = (short*)smem;

    int t = threadIdx.x;
    int lane = t & 63;
    int wid = t >> 6;
    int rowA = lane & 15;
    int kgrp = lane >> 4;
    int goff = wid * 32;
    int gc0 = goff + (lane & 15);
    int gc1 = gc0 + 16;
    float b1v0 = b1[gc0], b1v1 = b1[gc1];
    float b2v0 = b2[gc0], b2v1 = b2[gc1];
    int gp = t & 63;
    int sl = t >> 6;
    int g2 = gp * 2;

    for (int ai = 0; ai < APB; ai++) {
        int ba = blockIdx.x * APB + ai;
        int b = ba >> 10;
        const float* fsrc = fij + (size_t)ba * NN * NS;

        // ---- phase 0: every wave computes the same compaction ballot ----
        unsigned long long bal;
        {
            float r = rij[(size_t)ba * NN + lane];
            int mk = nmask[(size_t)ba * NN + lane];
            bool valid = (mk != 0) && (r <= 5.0f);
            bal = __ballot(valid);
            if (wid == 0 && valid) {
                int pos = __popcll(bal & ((1ULL << lane) - 1ULL));
                cOff[pos] = nbr[(size_t)ba * NN + lane] << 7;   // * NF
            }
        }
        int V = (int)__popcll(bal);
        int MT = (V + 15) >> 4;

        // ---- stage valid f_ij rows (bf16, XOR-swizzled) via compaction scatter ----
        {
            int n = t >> 2;
            if ((bal >> n) & 1ULL) {
                int pos = __popcll(bal & ((1ULL << n) - 1ULL));
                int k0 = (t & 3) * 16;
                const float4* src = (const float4*)(fsrc + (size_t)n * NS + k0);
                float4 a = src[0], bb = src[1], c = src[2], d = src[3];
                u32x4 lo = (u32x4){pkbf(a.x, a.y), pkbf(a.z, a.w), pkbf(bb.x, bb.y), pkbf(bb.z, bb.w)};
                u32x4 hi = (u32x4){pkbf(c.x, c.y), pkbf(c.z, c.w), pkbf(d.x, d.y), pkbf(d.z, d.w)};
                int base = pos * 128 + k0 * 2;
                int sw = (pos & 7) << 4;
                *(u32x4*)(smem + ((base) ^ sw))      = lo;
                *(u32x4*)(smem + ((base + 16) ^ sw)) = hi;
            }
        }
        __syncthreads();   // #1: fijL + cOff visible

        // ---- GEMM1: h = ssp(fij_c @ W1 + b1)  (M=MT*16, N=32/wave, K=64) ----
        f32x4 acc[4][2];
#pragma unroll
        for (int mt = 0; mt < 4; mt++) {
            acc[mt][0] = (f32x4){b1v0, b1v0, b1v0, b1v0};
            acc[mt][1] = (f32x4){b1v1, b1v1, b1v1, b1v1};
        }
#pragma unroll
        for (int kt = 0; kt < 2; kt++) {
            bf16x8 bf0 = *(const bf16x8*)&W1f[((kt * 8 + wid * 2 + 0) * 64 + lane) * 8];
            bf16x8 bf1 = *(const bf16x8*)&W1f[((kt * 8 + wid * 2 + 1) * 64 + lane) * 8];
#pragma unroll
            for (int mt = 0; mt < 4; mt++) {
                if (mt < MT) {
                    int row = mt * 16 + rowA;
                    int byte = (row * 128 + kt * 64 + kgrp * 16) ^ ((row & 7) << 4);
                    bf16x8 af = *(const bf16x8*)(smem + byte);
                    acc[mt][0] = __builtin_amdgcn_mfma_f32_16x16x32_bf16(af, bf0, acc[mt][0], 0, 0, 0);
                    acc[mt][1] = __builtin_amdgcn_mfma_f32_16x16x32_bf16(af, bf1, acc[mt][1], 0, 0, 0);
                }
            }
        }
        __syncthreads();   // #2: all fijL reads done; hL may overlay

        // ssp + store h (bf16) to hL
#pragma unroll
        for (int mt = 0; mt < 4; mt++) {
            if (mt < MT) {
#pragma unroll
                for (int nt = 0; nt < 2; nt++) {
                    int col = goff + nt * 16 + (lane & 15);
                    int row0 = mt * 16 + kgrp * 4;
                    unsigned p01 = pkbf(ssp(acc[mt][nt][0]), ssp(acc[mt][nt][1]));
                    unsigned p23 = pkbf(ssp(acc[mt][nt][2]), ssp(acc[mt][nt][3]));
                    hL[(row0 + 0) * HSTR + col] = (short)(p01 & 0xffffu);
                    hL[(row0 + 1) * HSTR + col] = (short)(p01 >> 16);
                    hL[(row0 + 2) * HSTR + col] = (short)(p23 & 0xffffu);
                    hL[(row0 + 3) * HSTR + col] = (short)(p23 >> 16);
                }
            }
        }
        __syncthreads();   // #3: h complete

        // ---- GEMM2: Wfilt = h @ W2 + b2  (M=MT*16, N=32/wave, K=128) ----
        f32x4 acc2[4][2];
#pragma unroll
        for (int mt = 0; mt < 4; mt++) {
            acc2[mt][0] = (f32x4){b2v0, b2v0, b2v0, b2v0};
            acc2[mt][1] = (f32x4){b2v1, b2v1, b2v1, b2v1};
        }
#pragma unroll
        for (int kt = 0; kt < 4; kt++) {
            bf16x8 bf0 = *(const bf16x8*)&W2f[((kt * 8 + wid * 2 + 0) * 64 + lane) * 8];
            bf16x8 bf1 = *(const bf16x8*)&W2f[((kt * 8 + wid * 2 + 1) * 64 + lane) * 8];
#pragma unroll
            for (int mt = 0; mt < 4; mt++) {
                if (mt < MT) {
                    bf16x8 af = *(const bf16x8*)&hL[(mt * 16 + rowA) * HSTR + kt * 32 + kgrp * 8];
                    acc2[mt][0] = __builtin_amdgcn_mfma_f32_16x16x32_bf16(af, bf0, acc2[mt][0], 0, 0, 0);
                    acc2[mt][1] = __builtin_amdgcn_mfma_f32_16x16x32_bf16(af, bf1, acc2[mt][1], 0, 0, 0);
                }
            }
        }
        __syncthreads();   // #4: hL reads done; wfB may overlay

        // Wfilt (bf16) -> wfB
#pragma unroll
        for (int mt = 0; mt < 4; mt++) {
            if (mt < MT) {
#pragma unroll
                for (int nt = 0; nt < 2; nt++) {
                    int col = goff + nt * 16 + (lane & 15);
                    int row0 = mt * 16 + kgrp * 4;
                    unsigned p01 = pkbf(acc2[mt][nt][0], acc2[mt][nt][1]);
                    unsigned p23 = pkbf(acc2[mt][nt][2], acc2[mt][nt][3]);
                    wfB[(row0 + 0) * HSTR + col] = (short)(p01 & 0xffffu);
                    wfB[(row0 + 1) * HSTR + col] = (short)(p01 >> 16);
                    wfB[(row0 + 2) * HSTR + col] = (short)(p23 & 0xffffu);
                    wfB[(row0 + 3) * HSTR + col] = (short)(p23 >> 16);
                }
            }
        }
        __syncthreads();   // #5

        // ---- gather y rows + reduce over valid neighbors (float2/lane, 4 j-slices) ----
        const float* yb = y + (size_t)b * NA * NF;
        float lx = 0.0f, ly = 0.0f;
#pragma unroll 4
        for (int j = sl; j < V; j += 4) {
            unsigned wv2 = *(const unsigned*)&wfB[j * HSTR + g2];
            float2 yv = *(const float2*)&yb[(size_t)cOff[j] + g2];
            lx = fmaf(yv.x, bf2f((short)(wv2 & 0xffffu)), lx);
            ly = fmaf(yv.y, bf2f((short)(wv2 >> 16)), ly);
        }
        red2[sl][gp] = (float2){lx, ly};
        __syncthreads();   // #6: also protects smem/cOff reuse next iteration
        if (t < 64) {
            float2 a0 = red2[0][t], a1 = red2[1][t], a2 = red2[2][t], a3 = red2[3][t];
            float2 s;
            s.x = (a0.x + a1.x) + (a2.x + a3.x);
            s.y = (a0.y + a1.y) + (a2.y + a3.y);
            *(float2*)&agg[(size_t)ba * NF + t * 2] = s;
        }
    }
}

extern "C" void kernel_launch(void* const* d_in, const int* in_sizes, int n_in,
                              void* d_out, int out_size, void* d_ws, size_t ws_size,
                              hipStream_t stream) {
    const float* x    = (const float*)d_in[0];
    const float* rij  = (const float*)d_in[1];
    const float* fij  = (const float*)d_in[2];
    const int*   nbr  = (const int*)d_in[3];
    const int*   nmask = (const int*)d_in[4];     // bool -> int32 per harness
    const float* W_in2f = (const float*)d_in[5];
    const float* W1   = (const float*)d_in[6];
    const float* b1   = (const float*)d_in[7];
    const float* W2   = (const float*)d_in[8];
    const float* b2   = (const float*)d_in[9];
    const float* Wf2  = (const float*)d_in[10];
    const float* bf2  = (const float*)d_in[11];
    const float* Wd   = (const float*)d_in[12];
    const float* bd   = (const float*)d_in[13];

    float* out = (float*)d_out;
    float* y   = (float*)d_ws;                                       // 4 MB f32 scratch
    short* W1f   = (short*)((char*)d_ws + (size_t)NB * NA * NF * 4); // 16 KB
    short* W2f   = W1f + NS * NF;                                    // 32 KB
    short* Winff = W2f + NF * NF;                                    // 32 KB
    short* Wf2f  = Winff + NF * NF;                                  // 32 KB
    short* Wdf   = Wf2f + NF * NF;                                   // 32 KB

    const int rows = NB * NA;   // 8192

    k_prep<<<64, 256, 0, stream>>>(W1, W2, W_in2f, Wf2, Wd, W1f, W2f, Winff, Wf2f, Wdf);
    k_in2f_m<<<rows / 32, 256, 0, stream>>>(x, Winff, y);
    k_conv<<<rows / APB, 256, 0, stream>>>(fij, rij, nbr, nmask, y, W1f, b1, W2f, b2, out);
    k_out_m<<<rows / 32, 256, 0, stream>>>(out, Wf2f, bf2, Wdf, bd);
}

// Round 16
// 71.751 us; speedup vs baseline: 1.5589x; 1.5589x over previous
//
#include <hip/hip_runtime.h>
#include <math.h>

#define NB 8
#define NA 1024
#define NN 64
#define NF 128
#define NS 64
#define LN2 0.69314718055994530942f
#define HSTR 136   // bf16 LDS row stride in elems: 272B rows, balanced b128 reads

typedef __attribute__((ext_vector_type(8))) short bf16x8;
typedef __attribute__((ext_vector_type(4))) float f32x4;
typedef __attribute__((ext_vector_type(4))) unsigned u32x4;
typedef __attribute__((ext_vector_type(2))) unsigned u32x2;

__device__ __forceinline__ float ssp(float x) {
    return fmaxf(x, 0.0f) + __logf(1.0f + __expf(-fabsf(x))) - LN2;
}
__device__ __forceinline__ short f2bf(float f) {      // RNE f32 -> bf16 (cold paths)
    unsigned u = __float_as_uint(f);
    u += 0x7fffu + ((u >> 16) & 1u);
    return (short)(u >> 16);
}
__device__ __forceinline__ unsigned pkbf(float a, float b) {   // packed RNE pair, 1 inst
    unsigned r;
    asm("v_cvt_pk_bf16_f32 %0, %1, %2" : "=v"(r) : "v"(a), "v"(b));
    return r;
}
__device__ __forceinline__ float bf2f(short s) {
    return __uint_as_float(((unsigned)(unsigned short)s) << 16);
}

// ---------------- prep: swizzle weights into MFMA B-fragment order (bf16) ----------------
__device__ __forceinline__ void swz_frag(const float* __restrict__ W, short* __restrict__ Wf, int t) {
    int k = t >> 7, n = t & 127;
    int kt = k >> 5, lg = (k >> 3) & 3, j = k & 7, ntg = n >> 4, col = n & 15;
    Wf[((kt * 8 + ntg) * 64 + (lg * 16 + col)) * 8 + j] = f2bf(W[t]);
}

__global__ __launch_bounds__(256) void k_prep(const float* __restrict__ W1,
                                              const float* __restrict__ W2,
                                              const float* __restrict__ Winf,
                                              const float* __restrict__ Wf2,
                                              const float* __restrict__ Wd,
                                              short* __restrict__ W1f, short* __restrict__ W2f,
                                              short* __restrict__ Winff, short* __restrict__ Wf2f,
                                              short* __restrict__ Wdf) {
    int t = blockIdx.x * 256 + threadIdx.x;   // 16384 threads == NF*NF
    if (t < NS * NF) swz_frag(W1, W1f, t);
    swz_frag(W2, W2f, t);
    swz_frag(Winf, Winff, t);
    swz_frag(Wf2, Wf2f, t);
    swz_frag(Wd, Wdf, t);
}

// ---- staging helper: 32 f32 rows (128 wide) -> bf16 LDS, XOR-swizzled, 256B rows ----
__device__ __forceinline__ void stage32(const float* __restrict__ src, char* __restrict__ dst, int t) {
    int row = t >> 3, seg = t & 7;
    const float4* sp = (const float4*)(src + (size_t)row * NF + seg * 16);
    float4 a = sp[0], b = sp[1], c = sp[2], d = sp[3];
    u32x4 lo = (u32x4){pkbf(a.x, a.y), pkbf(a.z, a.w), pkbf(b.x, b.y), pkbf(b.z, b.w)};
    u32x4 hi = (u32x4){pkbf(c.x, c.y), pkbf(c.z, c.w), pkbf(d.x, d.y), pkbf(d.z, d.w)};
    int base = row * 256 + seg * 32;
    int sw = (row & 7) << 4;
    *(u32x4*)(dst + ((base) ^ sw))      = lo;
    *(u32x4*)(dst + ((base + 16) ^ sw)) = hi;
}

// ---------------- kernel 1: y = x @ W_in2f (no bias), MFMA, M=32/block ----------------
__global__ __launch_bounds__(256) void k_in2f_m(const float* __restrict__ x,
                                                const short* __restrict__ Wf,
                                                float* __restrict__ y) {
    __shared__ __align__(16) char xL[32 * 256];   // 8 KB
    int t = threadIdx.x, lane = t & 63, wid = t >> 6;
    int row0 = blockIdx.x * 32;

    stage32(x + (size_t)row0 * NF, xL, t);
    __syncthreads();

    int rowA = lane & 15, kgrp = lane >> 4, goff = wid * 32;
    f32x4 acc[2][2];
#pragma unroll
    for (int mt = 0; mt < 2; mt++) {
        acc[mt][0] = (f32x4){0.f, 0.f, 0.f, 0.f};
        acc[mt][1] = (f32x4){0.f, 0.f, 0.f, 0.f};
    }
#pragma unroll
    for (int kt = 0; kt < 4; kt++) {
        bf16x8 bf0 = *(const bf16x8*)&Wf[((kt * 8 + wid * 2 + 0) * 64 + lane) * 8];
        bf16x8 bf1 = *(const bf16x8*)&Wf[((kt * 8 + wid * 2 + 1) * 64 + lane) * 8];
#pragma unroll
        for (int mt = 0; mt < 2; mt++) {
            int row = mt * 16 + rowA;
            int byte = (row * 256 + kt * 64 + kgrp * 16) ^ ((row & 7) << 4);
            bf16x8 af = *(const bf16x8*)(xL + byte);
            acc[mt][0] = __builtin_amdgcn_mfma_f32_16x16x32_bf16(af, bf0, acc[mt][0], 0, 0, 0);
            acc[mt][1] = __builtin_amdgcn_mfma_f32_16x16x32_bf16(af, bf1, acc[mt][1], 0, 0, 0);
        }
    }
#pragma unroll
    for (int mt = 0; mt < 2; mt++)
#pragma unroll
        for (int nt = 0; nt < 2; nt++)
#pragma unroll
            for (int r = 0; r < 4; r++)
                y[(size_t)(row0 + mt * 16 + kgrp * 4 + r) * NF + goff + nt * 16 + (lane & 15)] = acc[mt][nt][r];
}

// ---------------- kernel 3: buf = ssp(buf@Wf2+bf2) @ Wd + bd, MFMA, in place, M=32/block ----------------
__global__ __launch_bounds__(256) void k_out_m(float* buf,
                                               const short* __restrict__ Wf2f, const float* __restrict__ bf2,
                                               const short* __restrict__ Wdf, const float* __restrict__ bd) {
    __shared__ __align__(16) char xL[32 * 256];   // 8 KB (agg bf16)
    __shared__ short vL[32 * HSTR];               // 8.5 KB (v bf16)
    int t = threadIdx.x, lane = t & 63, wid = t >> 6;
    int row0 = blockIdx.x * 32;

    stage32(buf + (size_t)row0 * NF, xL, t);
    __syncthreads();

    int rowA = lane & 15, kgrp = lane >> 4, goff = wid * 32;
    int gc0 = goff + (lane & 15), gc1 = gc0 + 16;
    float bb0 = bf2[gc0], bb1 = bf2[gc1];

    // GEMM1: v = ssp(agg @ Wf2 + bf2)
    f32x4 acc[2][2];
#pragma unroll
    for (int mt = 0; mt < 2; mt++) {
        acc[mt][0] = (f32x4){bb0, bb0, bb0, bb0};
        acc[mt][1] = (f32x4){bb1, bb1, bb1, bb1};
    }
#pragma unroll
    for (int kt = 0; kt < 4; kt++) {
        bf16x8 bf0 = *(const bf16x8*)&Wf2f[((kt * 8 + wid * 2 + 0) * 64 + lane) * 8];
        bf16x8 bf1 = *(const bf16x8*)&Wf2f[((kt * 8 + wid * 2 + 1) * 64 + lane) * 8];
#pragma unroll
        for (int mt = 0; mt < 2; mt++) {
            int row = mt * 16 + rowA;
            int byte = (row * 256 + kt * 64 + kgrp * 16) ^ ((row & 7) << 4);
            bf16x8 af = *(const bf16x8*)(xL + byte);
            acc[mt][0] = __builtin_amdgcn_mfma_f32_16x16x32_bf16(af, bf0, acc[mt][0], 0, 0, 0);
            acc[mt][1] = __builtin_amdgcn_mfma_f32_16x16x32_bf16(af, bf1, acc[mt][1], 0, 0, 0);
        }
    }
    // ssp -> vL (bf16, HSTR rows)
#pragma unroll
    for (int mt = 0; mt < 2; mt++)
#pragma unroll
        for (int nt = 0; nt < 2; nt++) {
            int col = goff + nt * 16 + (lane & 15);
            int r0 = mt * 16 + kgrp * 4;
            unsigned p01 = pkbf(ssp(acc[mt][nt][0]), ssp(acc[mt][nt][1]));
            unsigned p23 = pkbf(ssp(acc[mt][nt][2]), ssp(acc[mt][nt][3]));
            vL[(r0 + 0) * HSTR + col] = (short)(p01 & 0xffffu);
            vL[(r0 + 1) * HSTR + col] = (short)(p01 >> 16);
            vL[(r0 + 2) * HSTR + col] = (short)(p23 & 0xffffu);
            vL[(r0 + 3) * HSTR + col] = (short)(p23 >> 16);
        }
    __syncthreads();

    // GEMM2: out = v @ Wd + bd
    float bd0 = bd[gc0], bd1 = bd[gc1];
    f32x4 acc2[2][2];
#pragma unroll
    for (int mt = 0; mt < 2; mt++) {
        acc2[mt][0] = (f32x4){bd0, bd0, bd0, bd0};
        acc2[mt][1] = (f32x4){bd1, bd1, bd1, bd1};
    }
#pragma unroll
    for (int kt = 0; kt < 4; kt++) {
        bf16x8 bf0 = *(const bf16x8*)&Wdf[((kt * 8 + wid * 2 + 0) * 64 + lane) * 8];
        bf16x8 bf1 = *(const bf16x8*)&Wdf[((kt * 8 + wid * 2 + 1) * 64 + lane) * 8];
#pragma unroll
        for (int mt = 0; mt < 2; mt++) {
            bf16x8 af = *(const bf16x8*)&vL[(mt * 16 + rowA) * HSTR + kt * 32 + kgrp * 8];
            acc2[mt][0] = __builtin_amdgcn_mfma_f32_16x16x32_bf16(af, bf0, acc2[mt][0], 0, 0, 0);
            acc2[mt][1] = __builtin_amdgcn_mfma_f32_16x16x32_bf16(af, bf1, acc2[mt][1], 0, 0, 0);
        }
    }
#pragma unroll
    for (int mt = 0; mt < 2; mt++)
#pragma unroll
        for (int nt = 0; nt < 2; nt++)
#pragma unroll
            for (int r = 0; r < 4; r++)
                buf[(size_t)(row0 + mt * 16 + kgrp * 4 + r) * NF + goff + nt * 16 + (lane & 15)] = acc2[mt][nt][r];
}

// ---------------- kernel 2: MFMA filter net + cfconv (R14 base, g-vectorized epilogue) ----------------
// one block per (b,a); 4 waves, wave wid owns g-slice [wid*32, wid*32+32)
// LDS: single 17.4K union — fijL [0,8192) -> (barrier) -> hL [0,17408) -> (barrier) -> wfB [0,17408)
__global__ __launch_bounds__(256) void k_conv(
        const float* __restrict__ fij, const float* __restrict__ rij,
        const int* __restrict__ nbr, const int* __restrict__ nmask,
        const float* __restrict__ y,
        const short* __restrict__ W1f, const float* __restrict__ b1,
        const short* __restrict__ W2f, const float* __restrict__ b2,
        float* __restrict__ agg) {
    __shared__ __align__(16) char smem[NN * HSTR * 2];   // 17408 B union
    __shared__ int cOff[NN];            // compacted neighbor row offset (premul NF)
    __shared__ f32x4 red4[8][NF / 4];   // 4 KB: 8 j-slices x 32 col-quads

    short* hL  = (short*)smem;
    short* wfB = (short*)smem;

    int t = threadIdx.x;
    int ba = blockIdx.x;
    int b = ba >> 10;
    int lane = t & 63;
    int wid = t >> 6;

    const float* fsrc = fij + (size_t)ba * NN * NS;

    // ---- phase 0: every wave computes the same compaction ballot ----
    unsigned long long bal;
    {
        float r = rij[(size_t)ba * NN + lane];
        int mk = nmask[(size_t)ba * NN + lane];
        bool valid = (mk != 0) && (r <= 5.0f);
        bal = __ballot(valid);
        if (wid == 0 && valid) {
            int pos = __popcll(bal & ((1ULL << lane) - 1ULL));
            cOff[pos] = nbr[(size_t)ba * NN + lane] << 7;   // * NF
        }
    }
    int V = (int)__popcll(bal);
    int MT = (V + 15) >> 4;

    // ---- stage valid f_ij rows (bf16, XOR-swizzled) via compaction scatter ----
    {
        int n = t >> 2;
        if ((bal >> n) & 1ULL) {
            int pos = __popcll(bal & ((1ULL << n) - 1ULL));
            int k0 = (t & 3) * 16;
            const float4* src = (const float4*)(fsrc + (size_t)n * NS + k0);
            float4 a = src[0], bb = src[1], c = src[2], d = src[3];
            u32x4 lo = (u32x4){pkbf(a.x, a.y), pkbf(a.z, a.w), pkbf(bb.x, bb.y), pkbf(bb.z, bb.w)};
            u32x4 hi = (u32x4){pkbf(c.x, c.y), pkbf(c.z, c.w), pkbf(d.x, d.y), pkbf(d.z, d.w)};
            int base = pos * 128 + k0 * 2;
            int sw = (pos & 7) << 4;
            *(u32x4*)(smem + ((base) ^ sw))      = lo;
            *(u32x4*)(smem + ((base + 16) ^ sw)) = hi;
        }
    }
    __syncthreads();   // #1: fijL + cOff visible

    int rowA = lane & 15;
    int kgrp = lane >> 4;
    int goff = wid * 32;

    int gc0 = goff + (lane & 15);
    int gc1 = gc0 + 16;
    float b1v0 = b1[gc0], b1v1 = b1[gc1];
    float b2v0 = b2[gc0], b2v1 = b2[gc1];

    // ---- GEMM1: h = ssp(fij_c @ W1 + b1)  (M=MT*16, N=32/wave, K=64) ----
    f32x4 acc[4][2];
#pragma unroll
    for (int mt = 0; mt < 4; mt++) {
        acc[mt][0] = (f32x4){b1v0, b1v0, b1v0, b1v0};
        acc[mt][1] = (f32x4){b1v1, b1v1, b1v1, b1v1};
    }
#pragma unroll
    for (int kt = 0; kt < 2; kt++) {
        bf16x8 bf0 = *(const bf16x8*)&W1f[((kt * 8 + wid * 2 + 0) * 64 + lane) * 8];
        bf16x8 bf1 = *(const bf16x8*)&W1f[((kt * 8 + wid * 2 + 1) * 64 + lane) * 8];
#pragma unroll
        for (int mt = 0; mt < 4; mt++) {
            if (mt < MT) {
                int row = mt * 16 + rowA;
                int byte = (row * 128 + kt * 64 + kgrp * 16) ^ ((row & 7) << 4);
                bf16x8 af = *(const bf16x8*)(smem + byte);
                acc[mt][0] = __builtin_amdgcn_mfma_f32_16x16x32_bf16(af, bf0, acc[mt][0], 0, 0, 0);
                acc[mt][1] = __builtin_amdgcn_mfma_f32_16x16x32_bf16(af, bf1, acc[mt][1], 0, 0, 0);
            }
        }
    }
    __syncthreads();   // #2: all fijL reads done; hL may overlay

    // ssp + store h (bf16) to hL
#pragma unroll
    for (int mt = 0; mt < 4; mt++) {
        if (mt < MT) {
#pragma unroll
            for (int nt = 0; nt < 2; nt++) {
                int col = goff + nt * 16 + (lane & 15);
                int row0 = mt * 16 + kgrp * 4;
                unsigned p01 = pkbf(ssp(acc[mt][nt][0]), ssp(acc[mt][nt][1]));
                unsigned p23 = pkbf(ssp(acc[mt][nt][2]), ssp(acc[mt][nt][3]));
                hL[(row0 + 0) * HSTR + col] = (short)(p01 & 0xffffu);
                hL[(row0 + 1) * HSTR + col] = (short)(p01 >> 16);
                hL[(row0 + 2) * HSTR + col] = (short)(p23 & 0xffffu);
                hL[(row0 + 3) * HSTR + col] = (short)(p23 >> 16);
            }
        }
    }
    __syncthreads();   // #3: h complete

    // ---- GEMM2: Wfilt = h @ W2 + b2  (M=MT*16, N=32/wave, K=128) ----
    f32x4 acc2[4][2];
#pragma unroll
    for (int mt = 0; mt < 4; mt++) {
        acc2[mt][0] = (f32x4){b2v0, b2v0, b2v0, b2v0};
        acc2[mt][1] = (f32x4){b2v1, b2v1, b2v1, b2v1};
    }
#pragma unroll
    for (int kt = 0; kt < 4; kt++) {
        bf16x8 bf0 = *(const bf16x8*)&W2f[((kt * 8 + wid * 2 + 0) * 64 + lane) * 8];
        bf16x8 bf1 = *(const bf16x8*)&W2f[((kt * 8 + wid * 2 + 1) * 64 + lane) * 8];
#pragma unroll
        for (int mt = 0; mt < 4; mt++) {
            if (mt < MT) {
                bf16x8 af = *(const bf16x8*)&hL[(mt * 16 + rowA) * HSTR + kt * 32 + kgrp * 8];
                acc2[mt][0] = __builtin_amdgcn_mfma_f32_16x16x32_bf16(af, bf0, acc2[mt][0], 0, 0, 0);
                acc2[mt][1] = __builtin_amdgcn_mfma_f32_16x16x32_bf16(af, bf1, acc2[mt][1], 0, 0, 0);
            }
        }
    }
    __syncthreads();   // #4: hL reads done; wfB may overlay

    // Wfilt (bf16) -> wfB
#pragma unroll
    for (int mt = 0; mt < 4; mt++) {
        if (mt < MT) {
#pragma unroll
            for (int nt = 0; nt < 2; nt++) {
                int col = goff + nt * 16 + (lane & 15);
                int row0 = mt * 16 + kgrp * 4;
                unsigned p01 = pkbf(acc2[mt][nt][0], acc2[mt][nt][1]);
                unsigned p23 = pkbf(acc2[mt][nt][2], acc2[mt][nt][3]);
                wfB[(row0 + 0) * HSTR + col] = (short)(p01 & 0xffffu);
                wfB[(row0 + 1) * HSTR + col] = (short)(p01 >> 16);
                wfB[(row0 + 2) * HSTR + col] = (short)(p23 & 0xffffu);
                wfB[(row0 + 3) * HSTR + col] = (short)(p23 >> 16);
            }
        }
    }
    __syncthreads();   // #5

    // ---- epilogue: g-vectorized gather (float4 y, b64 wf), 8 j-slices ----
    int quad = t & 31;        // col quad index: cols [4q, 4q+4)
    int sl = t >> 5;          // j-slice 0..7
    int g4 = quad * 4;
    const float* yb = y + (size_t)b * NA * NF;
    f32x4 lacc = (f32x4){0.f, 0.f, 0.f, 0.f};
    for (int j = sl; j < V; j += 8) {
        u32x2 wv = *(const u32x2*)&wfB[j * HSTR + g4];
        float4 yv = *(const float4*)&yb[(size_t)cOff[j] + g4];
        lacc[0] = fmaf(yv.x, bf2f((short)(wv[0] & 0xffffu)), lacc[0]);
        lacc[1] = fmaf(yv.y, bf2f((short)(wv[0] >> 16)),     lacc[1]);
        lacc[2] = fmaf(yv.z, bf2f((short)(wv[1] & 0xffffu)), lacc[2]);
        lacc[3] = fmaf(yv.w, bf2f((short)(wv[1] >> 16)),     lacc[3]);
    }
    red4[sl][quad] = lacc;
    __syncthreads();   // #6
    if (t < 32) {
        f32x4 s = red4[0][t];
#pragma unroll
        for (int k = 1; k < 8; k++) {
            f32x4 a = red4[k][t];
            s[0] += a[0]; s[1] += a[1]; s[2] += a[2]; s[3] += a[3];
        }
        *(f32x4*)&agg[(size_t)ba * NF + t * 4] = s;
    }
}

extern "C" void kernel_launch(void* const* d_in, const int* in_sizes, int n_in,
                              void* d_out, int out_size, void* d_ws, size_t ws_size,
                              hipStream_t stream) {
    const float* x    = (const float*)d_in[0];
    const float* rij  = (const float*)d_in[1];
    const float* fij  = (const float*)d_in[2];
    const int*   nbr  = (const int*)d_in[3];
    const int*   nmask = (const int*)d_in[4];     // bool -> int32 per harness
    const float* W_in2f = (const float*)d_in[5];
    const float* W1   = (const float*)d_in[6];
    const float* b1   = (const float*)d_in[7];
    const float* W2   = (const float*)d_in[8];
    const float* b2   = (const float*)d_in[9];
    const float* Wf2  = (const float*)d_in[10];
    const float* bf2  = (const float*)d_in[11];
    const float* Wd   = (const float*)d_in[12];
    const float* bd   = (const float*)d_in[13];

    float* out = (float*)d_out;
    float* y   = (float*)d_ws;                                       // 4 MB f32 scratch
    short* W1f   = (short*)((char*)d_ws + (size_t)NB * NA * NF * 4); // 16 KB
    short* W2f   = W1f + NS * NF;                                    // 32 KB
    short* Winff = W2f + NF * NF;                                    // 32 KB
    short* Wf2f  = Winff + NF * NF;                                  // 32 KB
    short* Wdf   = Wf2f + NF * NF;                                   // 32 KB

    const int rows = NB * NA;   // 8192

    k_prep<<<64, 256, 0, stream>>>(W1, W2, W_in2f, Wf2, Wd, W1f, W2f, Winff, Wf2f, Wdf);
    k_in2f_m<<<rows / 32, 256, 0, stream>>>(x, Winff, y);
    k_conv<<<rows, 256, 0, stream>>>(fij, rij, nbr, nmask, y, W1f, b1, W2f, b2, out);
    k_out_m<<<rows / 32, 256, 0, stream>>>(out, Wf2f, bf2, Wdf, bd);
}

// Round 17
// 71.244 us; speedup vs baseline: 1.5699x; 1.0071x over previous
//
#include <hip/hip_runtime.h>
#include <math.h>

#define NB 8
#define NA 1024
#define NN 64
#define NF 128
#define NS 64
#define LN2 0.69314718055994530942f
#define HSTR 136   // bf16 LDS row stride in elems: 272B rows, balanced b128 reads

typedef __attribute__((ext_vector_type(8))) short bf16x8;
typedef __attribute__((ext_vector_type(4))) float f32x4;
typedef __attribute__((ext_vector_type(4))) unsigned u32x4;
typedef __attribute__((ext_vector_type(2))) unsigned u32x2;

__device__ __forceinline__ float ssp(float x) {
    return fmaxf(x, 0.0f) + __logf(1.0f + __expf(-fabsf(x))) - LN2;
}
__device__ __forceinline__ short f2bf(float f) {      // RNE f32 -> bf16 (cold paths)
    unsigned u = __float_as_uint(f);
    u += 0x7fffu + ((u >> 16) & 1u);
    return (short)(u >> 16);
}
__device__ __forceinline__ unsigned pkbf(float a, float b) {   // packed RNE pair, 1 inst
    unsigned r;
    asm("v_cvt_pk_bf16_f32 %0, %1, %2" : "=v"(r) : "v"(a), "v"(b));
    return r;
}
__device__ __forceinline__ float bf2f(short s) {
    return __uint_as_float(((unsigned)(unsigned short)s) << 16);
}

// ---------------- prep: swizzle weights into MFMA B-fragment order (bf16) ----------------
__device__ __forceinline__ void swz_frag(const float* __restrict__ W, short* __restrict__ Wf, int t) {
    int k = t >> 7, n = t & 127;
    int kt = k >> 5, lg = (k >> 3) & 3, j = k & 7, ntg = n >> 4, col = n & 15;
    Wf[((kt * 8 + ntg) * 64 + (lg * 16 + col)) * 8 + j] = f2bf(W[t]);
}

__global__ __launch_bounds__(256) void k_prep(const float* __restrict__ W1,
                                              const float* __restrict__ W2,
                                              const float* __restrict__ Winf,
                                              const float* __restrict__ Wf2,
                                              const float* __restrict__ Wd,
                                              short* __restrict__ W1f, short* __restrict__ W2f,
                                              short* __restrict__ Winff, short* __restrict__ Wf2f,
                                              short* __restrict__ Wdf) {
    int t = blockIdx.x * 256 + threadIdx.x;   // 16384 threads == NF*NF
    if (t < NS * NF) swz_frag(W1, W1f, t);
    swz_frag(W2, W2f, t);
    swz_frag(Winf, Winff, t);
    swz_frag(Wf2, Wf2f, t);
    swz_frag(Wd, Wdf, t);
}

// ---- staging helper: 32 f32 rows (128 wide) -> bf16 LDS, XOR-swizzled, 256B rows ----
__device__ __forceinline__ void stage32(const float* __restrict__ src, char* __restrict__ dst, int t) {
    int row = t >> 3, seg = t & 7;
    const float4* sp = (const float4*)(src + (size_t)row * NF + seg * 16);
    float4 a = sp[0], b = sp[1], c = sp[2], d = sp[3];
    u32x4 lo = (u32x4){pkbf(a.x, a.y), pkbf(a.z, a.w), pkbf(b.x, b.y), pkbf(b.z, b.w)};
    u32x4 hi = (u32x4){pkbf(c.x, c.y), pkbf(c.z, c.w), pkbf(d.x, d.y), pkbf(d.z, d.w)};
    int base = row * 256 + seg * 32;
    int sw = (row & 7) << 4;
    *(u32x4*)(dst + ((base) ^ sw))      = lo;
    *(u32x4*)(dst + ((base + 16) ^ sw)) = hi;
}

// ---------------- kernel 1: y = x @ W_in2f (no bias), MFMA, M=32/block ----------------
__global__ __launch_bounds__(256) void k_in2f_m(const float* __restrict__ x,
                                                const short* __restrict__ Wf,
                                                float* __restrict__ y) {
    __shared__ __align__(16) char xL[32 * 256];   // 8 KB
    int t = threadIdx.x, lane = t & 63, wid = t >> 6;
    int row0 = blockIdx.x * 32;

    stage32(x + (size_t)row0 * NF, xL, t);
    __syncthreads();

    int rowA = lane & 15, kgrp = lane >> 4, goff = wid * 32;
    f32x4 acc[2][2];
#pragma unroll
    for (int mt = 0; mt < 2; mt++) {
        acc[mt][0] = (f32x4){0.f, 0.f, 0.f, 0.f};
        acc[mt][1] = (f32x4){0.f, 0.f, 0.f, 0.f};
    }
#pragma unroll
    for (int kt = 0; kt < 4; kt++) {
        bf16x8 bf0 = *(const bf16x8*)&Wf[((kt * 8 + wid * 2 + 0) * 64 + lane) * 8];
        bf16x8 bf1 = *(const bf16x8*)&Wf[((kt * 8 + wid * 2 + 1) * 64 + lane) * 8];
#pragma unroll
        for (int mt = 0; mt < 2; mt++) {
            int row = mt * 16 + rowA;
            int byte = (row * 256 + kt * 64 + kgrp * 16) ^ ((row & 7) << 4);
            bf16x8 af = *(const bf16x8*)(xL + byte);
            acc[mt][0] = __builtin_amdgcn_mfma_f32_16x16x32_bf16(af, bf0, acc[mt][0], 0, 0, 0);
            acc[mt][1] = __builtin_amdgcn_mfma_f32_16x16x32_bf16(af, bf1, acc[mt][1], 0, 0, 0);
        }
    }
#pragma unroll
    for (int mt = 0; mt < 2; mt++)
#pragma unroll
        for (int nt = 0; nt < 2; nt++)
#pragma unroll
            for (int r = 0; r < 4; r++)
                y[(size_t)(row0 + mt * 16 + kgrp * 4 + r) * NF + goff + nt * 16 + (lane & 15)] = acc[mt][nt][r];
}

// ---------------- kernel 3: buf = ssp(buf@Wf2+bf2) @ Wd + bd, MFMA, in place, M=32/block ----------------
__global__ __launch_bounds__(256) void k_out_m(float* buf,
                                               const short* __restrict__ Wf2f, const float* __restrict__ bf2,
                                               const short* __restrict__ Wdf, const float* __restrict__ bd) {
    __shared__ __align__(16) char xL[32 * 256];   // 8 KB (agg bf16)
    __shared__ short vL[32 * HSTR];               // 8.5 KB (v bf16)
    int t = threadIdx.x, lane = t & 63, wid = t >> 6;
    int row0 = blockIdx.x * 32;

    stage32(buf + (size_t)row0 * NF, xL, t);
    __syncthreads();

    int rowA = lane & 15, kgrp = lane >> 4, goff = wid * 32;
    int gc0 = goff + (lane & 15), gc1 = gc0 + 16;
    float bb0 = bf2[gc0], bb1 = bf2[gc1];

    // GEMM1: v = ssp(agg @ Wf2 + bf2)
    f32x4 acc[2][2];
#pragma unroll
    for (int mt = 0; mt < 2; mt++) {
        acc[mt][0] = (f32x4){bb0, bb0, bb0, bb0};
        acc[mt][1] = (f32x4){bb1, bb1, bb1, bb1};
    }
#pragma unroll
    for (int kt = 0; kt < 4; kt++) {
        bf16x8 bf0 = *(const bf16x8*)&Wf2f[((kt * 8 + wid * 2 + 0) * 64 + lane) * 8];
        bf16x8 bf1 = *(const bf16x8*)&Wf2f[((kt * 8 + wid * 2 + 1) * 64 + lane) * 8];
#pragma unroll
        for (int mt = 0; mt < 2; mt++) {
            int row = mt * 16 + rowA;
            int byte = (row * 256 + kt * 64 + kgrp * 16) ^ ((row & 7) << 4);
            bf16x8 af = *(const bf16x8*)(xL + byte);
            acc[mt][0] = __builtin_amdgcn_mfma_f32_16x16x32_bf16(af, bf0, acc[mt][0], 0, 0, 0);
            acc[mt][1] = __builtin_amdgcn_mfma_f32_16x16x32_bf16(af, bf1, acc[mt][1], 0, 0, 0);
        }
    }
    // ssp -> vL (bf16, HSTR rows)
#pragma unroll
    for (int mt = 0; mt < 2; mt++)
#pragma unroll
        for (int nt = 0; nt < 2; nt++) {
            int col = goff + nt * 16 + (lane & 15);
            int r0 = mt * 16 + kgrp * 4;
            unsigned p01 = pkbf(ssp(acc[mt][nt][0]), ssp(acc[mt][nt][1]));
            unsigned p23 = pkbf(ssp(acc[mt][nt][2]), ssp(acc[mt][nt][3]));
            vL[(r0 + 0) * HSTR + col] = (short)(p01 & 0xffffu);
            vL[(r0 + 1) * HSTR + col] = (short)(p01 >> 16);
            vL[(r0 + 2) * HSTR + col] = (short)(p23 & 0xffffu);
            vL[(r0 + 3) * HSTR + col] = (short)(p23 >> 16);
        }
    __syncthreads();

    // GEMM2: out = v @ Wd + bd
    float bd0 = bd[gc0], bd1 = bd[gc1];
    f32x4 acc2[2][2];
#pragma unroll
    for (int mt = 0; mt < 2; mt++) {
        acc2[mt][0] = (f32x4){bd0, bd0, bd0, bd0};
        acc2[mt][1] = (f32x4){bd1, bd1, bd1, bd1};
    }
#pragma unroll
    for (int kt = 0; kt < 4; kt++) {
        bf16x8 bf0 = *(const bf16x8*)&Wdf[((kt * 8 + wid * 2 + 0) * 64 + lane) * 8];
        bf16x8 bf1 = *(const bf16x8*)&Wdf[((kt * 8 + wid * 2 + 1) * 64 + lane) * 8];
#pragma unroll
        for (int mt = 0; mt < 2; mt++) {
            bf16x8 af = *(const bf16x8*)&vL[(mt * 16 + rowA) * HSTR + kt * 32 + kgrp * 8];
            acc2[mt][0] = __builtin_amdgcn_mfma_f32_16x16x32_bf16(af, bf0, acc2[mt][0], 0, 0, 0);
            acc2[mt][1] = __builtin_amdgcn_mfma_f32_16x16x32_bf16(af, bf1, acc2[mt][1], 0, 0, 0);
        }
    }
#pragma unroll
    for (int mt = 0; mt < 2; mt++)
#pragma unroll
        for (int nt = 0; nt < 2; nt++)
#pragma unroll
            for (int r = 0; r < 4; r++)
                buf[(size_t)(row0 + mt * 16 + kgrp * 4 + r) * NF + goff + nt * 16 + (lane & 15)] = acc2[mt][nt][r];
}

// ---------------- kernel 2: MFMA filter net + cfconv (5-barrier, disjoint hL) ----------------
// one block per (b,a); 4 waves, wave wid owns g-slice [wid*32, wid*32+32)
// LDS: fijL [0,8192) | hL [8192,25600) disjoint — h-store needs NO barrier vs GEMM1.
// wfB = hL region, overwritten in place after GEMM2's barrier.
__global__ __launch_bounds__(256) void k_conv(
        const float* __restrict__ fij, const float* __restrict__ rij,
        const int* __restrict__ nbr, const int* __restrict__ nmask,
        const float* __restrict__ y,
        const short* __restrict__ W1f, const float* __restrict__ b1,
        const short* __restrict__ W2f, const float* __restrict__ b2,
        float* __restrict__ agg) {
    __shared__ __align__(16) char smem[8192 + NN * HSTR * 2];   // 25600 B
    __shared__ int cOff[NN];            // compacted neighbor row offset (premul NF)
    __shared__ f32x4 red4[8][NF / 4];   // 4 KB: 8 j-slices x 32 col-quads

    short* hL  = (short*)(smem + 8192);
    short* wfB = hL;                    // in-place overwrite after barrier #3

    int t = threadIdx.x;
    int ba = blockIdx.x;
    int b = ba >> 10;
    int lane = t & 63;
    int wid = t >> 6;

    const float* fsrc = fij + (size_t)ba * NN * NS;

    // ---- phase 0: every wave computes the same compaction ballot ----
    unsigned long long bal;
    {
        float r = rij[(size_t)ba * NN + lane];
        int mk = nmask[(size_t)ba * NN + lane];
        bool valid = (mk != 0) && (r <= 5.0f);
        bal = __ballot(valid);
        if (wid == 0 && valid) {
            int pos = __popcll(bal & ((1ULL << lane) - 1ULL));
            cOff[pos] = nbr[(size_t)ba * NN + lane] << 7;   // * NF
        }
    }
    int V = (int)__popcll(bal);
    int MT = (V + 15) >> 4;

    // ---- stage valid f_ij rows (bf16, XOR-swizzled) via compaction scatter ----
    {
        int n = t >> 2;
        if ((bal >> n) & 1ULL) {
            int pos = __popcll(bal & ((1ULL << n) - 1ULL));
            int k0 = (t & 3) * 16;
            const float4* src = (const float4*)(fsrc + (size_t)n * NS + k0);
            float4 a = src[0], bb = src[1], c = src[2], d = src[3];
            u32x4 lo = (u32x4){pkbf(a.x, a.y), pkbf(a.z, a.w), pkbf(bb.x, bb.y), pkbf(bb.z, bb.w)};
            u32x4 hi = (u32x4){pkbf(c.x, c.y), pkbf(c.z, c.w), pkbf(d.x, d.y), pkbf(d.z, d.w)};
            int base = pos * 128 + k0 * 2;
            int sw = (pos & 7) << 4;
            *(u32x4*)(smem + ((base) ^ sw))      = lo;
            *(u32x4*)(smem + ((base + 16) ^ sw)) = hi;
        }
    }
    __syncthreads();   // #1: fijL + cOff visible

    int rowA = lane & 15;
    int kgrp = lane >> 4;
    int goff = wid * 32;

    int gc0 = goff + (lane & 15);
    int gc1 = gc0 + 16;
    float b1v0 = b1[gc0], b1v1 = b1[gc1];
    float b2v0 = b2[gc0], b2v1 = b2[gc1];

    // ---- GEMM1: h = ssp(fij_c @ W1 + b1)  (M=MT*16, N=32/wave, K=64) ----
    f32x4 acc[4][2];
#pragma unroll
    for (int mt = 0; mt < 4; mt++) {
        acc[mt][0] = (f32x4){b1v0, b1v0, b1v0, b1v0};
        acc[mt][1] = (f32x4){b1v1, b1v1, b1v1, b1v1};
    }
#pragma unroll
    for (int kt = 0; kt < 2; kt++) {
        bf16x8 bf0 = *(const bf16x8*)&W1f[((kt * 8 + wid * 2 + 0) * 64 + lane) * 8];
        bf16x8 bf1 = *(const bf16x8*)&W1f[((kt * 8 + wid * 2 + 1) * 64 + lane) * 8];
#pragma unroll
        for (int mt = 0; mt < 4; mt++) {
            if (mt < MT) {
                int row = mt * 16 + rowA;
                int byte = (row * 128 + kt * 64 + kgrp * 16) ^ ((row & 7) << 4);
                bf16x8 af = *(const bf16x8*)(smem + byte);
                acc[mt][0] = __builtin_amdgcn_mfma_f32_16x16x32_bf16(af, bf0, acc[mt][0], 0, 0, 0);
                acc[mt][1] = __builtin_amdgcn_mfma_f32_16x16x32_bf16(af, bf1, acc[mt][1], 0, 0, 0);
            }
        }
    }
    // NO barrier here: hL is disjoint from fijL — other waves' GEMM1 reads are safe.

    // ssp + store h (bf16) to hL
#pragma unroll
    for (int mt = 0; mt < 4; mt++) {
        if (mt < MT) {
#pragma unroll
            for (int nt = 0; nt < 2; nt++) {
                int col = goff + nt * 16 + (lane & 15);
                int row0 = mt * 16 + kgrp * 4;
                unsigned p01 = pkbf(ssp(acc[mt][nt][0]), ssp(acc[mt][nt][1]));
                unsigned p23 = pkbf(ssp(acc[mt][nt][2]), ssp(acc[mt][nt][3]));
                hL[(row0 + 0) * HSTR + col] = (short)(p01 & 0xffffu);
                hL[(row0 + 1) * HSTR + col] = (short)(p01 >> 16);
                hL[(row0 + 2) * HSTR + col] = (short)(p23 & 0xffffu);
                hL[(row0 + 3) * HSTR + col] = (short)(p23 >> 16);
            }
        }
    }
    __syncthreads();   // #2: h complete

    // ---- GEMM2: Wfilt = h @ W2 + b2  (M=MT*16, N=32/wave, K=128) ----
    f32x4 acc2[4][2];
#pragma unroll
    for (int mt = 0; mt < 4; mt++) {
        acc2[mt][0] = (f32x4){b2v0, b2v0, b2v0, b2v0};
        acc2[mt][1] = (f32x4){b2v1, b2v1, b2v1, b2v1};
    }
#pragma unroll
    for (int kt = 0; kt < 4; kt++) {
        bf16x8 bf0 = *(const bf16x8*)&W2f[((kt * 8 + wid * 2 + 0) * 64 + lane) * 8];
        bf16x8 bf1 = *(const bf16x8*)&W2f[((kt * 8 + wid * 2 + 1) * 64 + lane) * 8];
#pragma unroll
        for (int mt = 0; mt < 4; mt++) {
            if (mt < MT) {
                bf16x8 af = *(const bf16x8*)&hL[(mt * 16 + rowA) * HSTR + kt * 32 + kgrp * 8];
                acc2[mt][0] = __builtin_amdgcn_mfma_f32_16x16x32_bf16(af, bf0, acc2[mt][0], 0, 0, 0);
                acc2[mt][1] = __builtin_amdgcn_mfma_f32_16x16x32_bf16(af, bf1, acc2[mt][1], 0, 0, 0);
            }
        }
    }
    __syncthreads();   // #3: hL reads done; wfB may overwrite in place

    // Wfilt (bf16) -> wfB
#pragma unroll
    for (int mt = 0; mt < 4; mt++) {
        if (mt < MT) {
#pragma unroll
            for (int nt = 0; nt < 2; nt++) {
                int col = goff + nt * 16 + (lane & 15);
                int row0 = mt * 16 + kgrp * 4;
                unsigned p01 = pkbf(acc2[mt][nt][0], acc2[mt][nt][1]);
                unsigned p23 = pkbf(acc2[mt][nt][2], acc2[mt][nt][3]);
                wfB[(row0 + 0) * HSTR + col] = (short)(p01 & 0xffffu);
                wfB[(row0 + 1) * HSTR + col] = (short)(p01 >> 16);
                wfB[(row0 + 2) * HSTR + col] = (short)(p23 & 0xffffu);
                wfB[(row0 + 3) * HSTR + col] = (short)(p23 >> 16);
            }
        }
    }
    __syncthreads();   // #4

    // ---- epilogue: g-vectorized gather (float4 y, b64 wf), 8 j-slices ----
    int quad = t & 31;        // col quad index: cols [4q, 4q+4)
    int sl = t >> 5;          // j-slice 0..7
    int g4 = quad * 4;
    const float* yb = y + (size_t)b * NA * NF;
    f32x4 lacc = (f32x4){0.f, 0.f, 0.f, 0.f};
    for (int j = sl; j < V; j += 8) {
        u32x2 wv = *(const u32x2*)&wfB[j * HSTR + g4];
        float4 yv = *(const float4*)&yb[(size_t)cOff[j] + g4];
        lacc[0] = fmaf(yv.x, bf2f((short)(wv[0] & 0xffffu)), lacc[0]);
        lacc[1] = fmaf(yv.y, bf2f((short)(wv[0] >> 16)),     lacc[1]);
        lacc[2] = fmaf(yv.z, bf2f((short)(wv[1] & 0xffffu)), lacc[2]);
        lacc[3] = fmaf(yv.w, bf2f((short)(wv[1] >> 16)),     lacc[3]);
    }
    red4[sl][quad] = lacc;
    __syncthreads();   // #5
    if (t < 32) {
        f32x4 s = red4[0][t];
#pragma unroll
        for (int k = 1; k < 8; k++) {
            f32x4 a = red4[k][t];
            s[0] += a[0]; s[1] += a[1]; s[2] += a[2]; s[3] += a[3];
        }
        *(f32x4*)&agg[(size_t)ba * NF + t * 4] = s;
    }
}

extern "C" void kernel_launch(void* const* d_in, const int* in_sizes, int n_in,
                              void* d_out, int out_size, void* d_ws, size_t ws_size,
                              hipStream_t stream) {
    const float* x    = (const float*)d_in[0];
    const float* rij  = (const float*)d_in[1];
    const float* fij  = (const float*)d_in[2];
    const int*   nbr  = (const int*)d_in[3];
    const int*   nmask = (const int*)d_in[4];     // bool -> int32 per harness
    const float* W_in2f = (const float*)d_in[5];
    const float* W1   = (const float*)d_in[6];
    const float* b1   = (const float*)d_in[7];
    const float* W2   = (const float*)d_in[8];
    const float* b2   = (const float*)d_in[9];
    const float* Wf2  = (const float*)d_in[10];
    const float* bf2  = (const float*)d_in[11];
    const float* Wd   = (const float*)d_in[12];
    const float* bd   = (const float*)d_in[13];

    float* out = (float*)d_out;
    float* y   = (float*)d_ws;                                       // 4 MB f32 scratch
    short* W1f   = (short*)((char*)d_ws + (size_t)NB * NA * NF * 4); // 16 KB
    short* W2f   = W1f + NS * NF;                                    // 32 KB
    short* Winff = W2f + NF * NF;                                    // 32 KB
    short* Wf2f  = Winff + NF * NF;                                  // 32 KB
    short* Wdf   = Wf2f + NF * NF;                                   // 32 KB

    const int rows = NB * NA;   // 8192

    k_prep<<<64, 256, 0, stream>>>(W1, W2, W_in2f, Wf2, Wd, W1f, W2f, Winff, Wf2f, Wdf);
    k_in2f_m<<<rows / 32, 256, 0, stream>>>(x, Winff, y);
    k_conv<<<rows, 256, 0, stream>>>(fij, rij, nbr, nmask, y, W1f, b1, W2f, b2, out);
    k_out_m<<<rows / 32, 256, 0, stream>>>(out, Wf2f, bf2, Wdf, bd);
}